// Round 7
// baseline (56.757 us; speedup 1.0000x reference)
//
#include <hip/hip_runtime.h>

// out[b, t, w, c] = x[b, t + w - 9, c] (zero outside [0, T)), x: [32, 4096, 30] f32.
// Per (b,t) the 570-float output row equals the contiguous x span starting at
// (t-9)*30. Row-pair (t even) = 1140 floats = 285 float4 units, 16B-aligned.
// R6 confirmed wave-contiguous stream clustering as the lever (4KB/wave:
// 64.6->56.2us). This round: 8KB sequential span per wave (8 back-to-back 1KB
// wave-stores). Each 16B store is built from two float2 loads (a float2 never
// straddles a row: 570 even; one validity check per float2).

typedef float f32x4 __attribute__((ext_vector_type(4)));

constexpr int B   = 32;
constexpr int T   = 4096;          // power of 2
constexpr int C   = 30;
constexpr int PAD = 9;             // W/2
constexpr int ROW = 570;           // W*C floats per output row
constexpr int TC  = T * C;         // 122880 floats per batch of x
constexpr int PAIR_F4 = 285;       // float4 units per row-pair (1140 floats)
constexpr unsigned NPAIRS = (unsigned)B * (T / 2);   // 65536 row-pairs
constexpr unsigned TOTAL4 = NPAIRS * PAIR_F4;        // 18,662,400 float4 units
constexpr int UNROLL = 8;          // wave covers 512 units = 8KB sequential
// TOTAL4 / 512 = 36,450 waves exactly; 2 waves/block (128 thr) -> 18,225 blocks.

__global__ __launch_bounds__(128)
void OverlapTimeWindowLayer_kernel(const float* __restrict__ x,
                                   f32x4* __restrict__ out) {
    const unsigned g    = blockIdx.x * 128u + threadIdx.x;
    const unsigned wave = g >> 6;
    const int      lane = (int)(g & 63u);
    const unsigned vbase = wave * (64u * UNROLL) + (unsigned)lane;  // unit for k=0
#pragma unroll
    for (int k = 0; k < UNROLL; ++k) {
        const unsigned v = vbase + (unsigned)(64 * k);  // wave-contiguous 1KB each
        const unsigned p = v / PAIR_F4;            // row-pair index (magic-mul div)
        const int u  = (int)(v - p * PAIR_F4);     // float4 unit within pair [0,285)
        const int b  = (int)(p >> 11);             // / (T/2)
        const int tp = (int)(p & 2047);            // pair's first row is t = 2*tp
        const int base = (2 * tp - PAD) * C;       // source offset of row t
        const int e0 = 4 * u;                      // element offset within pair
        const float* xb = x + (unsigned)b * TC;

        // If element e >= ROW it belongs to row t+1: source -= (ROW - C).
        const int s0 = base + e0     - (e0     >= ROW ? (ROW - C) : 0);
        const int s1 = base + e0 + 2 - (e0 + 2 >= ROW ? (ROW - C) : 0);

        float2 lo = make_float2(0.0f, 0.0f);
        float2 hi = make_float2(0.0f, 0.0f);
        if (s0 >= 0 && s0 < TC) lo = *reinterpret_cast<const float2*>(xb + s0);
        if (s1 >= 0 && s1 < TC) hi = *reinterpret_cast<const float2*>(xb + s1);

        f32x4 val;
        val.x = lo.x; val.y = lo.y; val.z = hi.x; val.w = hi.y;
        out[v] = val;
    }
}

extern "C" void kernel_launch(void* const* d_in, const int* in_sizes, int n_in,
                              void* d_out, int out_size, void* d_ws, size_t ws_size,
                              hipStream_t stream) {
    const float* x = (const float*)d_in[0];
    f32x4* out = (f32x4*)d_out;
    const int block = 128;
    const unsigned grid = TOTAL4 / (64u * (unsigned)UNROLL * 2u);  // 18,225 blocks
    OverlapTimeWindowLayer_kernel<<<grid, block, 0, stream>>>(x, out);
}